// Round 1
// baseline (784.890 us; speedup 1.0000x reference)
//
#include <hip/hip_runtime.h>

// Problem geometry (compile-time constants from the reference):
// x: (1, 64, 32, 64, 64) f32   -> upsample 2x2x2 -> (1,64,64,128,128)
// y = einsum('ncdhw,oc->nodhw', u, W) + b
// z: (1, 64, 68, 132, 132) f32 -> center crop to (1,64,64,128,128)
// out = concat([y, zc], axis=1): (1, 128, 64, 128, 128) f32

#define XC   64
#define XD   32
#define XH   64
#define XW   64
#define XPL  (XD * XH * XW)        // 131072 floats per input channel

#define OD   64
#define OH   128
#define OW   128
#define OCH_STRIDE ((size_t)OD * OH * OW)   // 1,048,576 floats per out channel

#define ZD   68
#define ZH   132
#define ZW   132

// ---------------------------------------------------------------------------
// Kernel 1: upsample + 1x1x1 conv.
// One thread per x spatial position (d,h,w). Each thread loads all 64 input
// channels into registers (coalesced: lane index == w), computes 32 output
// channels (o-range split across blockIdx.y), and writes each result to its
// 2x2x2 replicated output block as float2 (lanes -> consecutive float2).
// ---------------------------------------------------------------------------
__global__ __launch_bounds__(256) void upconv_kernel(
    const float* __restrict__ x, const float* __restrict__ W,
    const float* __restrict__ b, float* __restrict__ out) {
  const int pos = blockIdx.x * 256 + threadIdx.x;   // 0 .. 131071
  const int w = pos & 63;
  const int h = (pos >> 6) & 63;
  const int d = pos >> 12;

  float xv[XC];
#pragma unroll
  for (int c = 0; c < XC; ++c) {
    xv[c] = x[(size_t)c * XPL + pos];
  }

  // Output spatial base for (2d, 2h, 2w)
  const size_t obase = ((size_t)(2 * d) * OH + (2 * h)) * OW + (2 * w);

  const int o_begin = blockIdx.y * 32;   // o-split of 2 for occupancy
#pragma unroll 4
  for (int oi = 0; oi < 32; ++oi) {
    const int o = o_begin + oi;
    float acc = b[o];
#pragma unroll
    for (int c = 0; c < XC; ++c) {
      acc += W[o * XC + c] * xv[c];      // wave-uniform -> scalar loads
    }
    const float2 v = make_float2(acc, acc);
    float* p = out + (size_t)o * OCH_STRIDE + obase;
    *(float2*)(p)                = v;    // (2d,   2h,   2w..2w+1)
    *(float2*)(p + OW)           = v;    // (2d,   2h+1, ...)
    *(float2*)(p + OH * OW)      = v;    // (2d+1, 2h,   ...)
    *(float2*)(p + OH * OW + OW) = v;    // (2d+1, 2h+1, ...)
  }
}

// ---------------------------------------------------------------------------
// Kernel 2: center-crop z -> out channels 64..127.
// Each thread moves 4 consecutive w floats. Source rows start at an 8-mod-16
// byte address, so use 2x float2 loads; dest is 16B-aligned -> float4 store.
// Total thread-units: 64ch * 64d * 128h * 32(w/4) = 2^24.
// ---------------------------------------------------------------------------
__global__ __launch_bounds__(256) void cropcat_kernel(
    const float* __restrict__ z, float* __restrict__ out) {
  const unsigned u = blockIdx.x * 256u + threadIdx.x;  // 0 .. 2^24-1
  const int w4 = (u & 31) << 2;
  const int h  = (u >> 5) & 127;
  const int d  = (u >> 12) & 63;
  const int c  = u >> 18;

  const float* src = z + ((size_t)((c * ZD + d + 2) * ZH + (h + 2))) * ZW + (w4 + 2);
  const float2 a  = *(const float2*)(src);
  const float2 bb = *(const float2*)(src + 2);

  float* dst = out + (size_t)(64 + c) * OCH_STRIDE + ((size_t)d * OH + h) * OW + w4;
  *(float4*)dst = make_float4(a.x, a.y, bb.x, bb.y);
}

extern "C" void kernel_launch(void* const* d_in, const int* in_sizes, int n_in,
                              void* d_out, int out_size, void* d_ws, size_t ws_size,
                              hipStream_t stream) {
  const float* x = (const float*)d_in[0];
  const float* z = (const float*)d_in[1];
  const float* W = (const float*)d_in[2];
  const float* b = (const float*)d_in[3];
  float* out = (float*)d_out;

  // Kernel 1: 131072 positions / 256 threads = 512 blocks, x2 o-split
  dim3 grid1(512, 2);
  upconv_kernel<<<grid1, 256, 0, stream>>>(x, W, b, out);

  // Kernel 2: 2^24 thread-units / 256 = 65536 blocks
  cropcat_kernel<<<65536, 256, 0, stream>>>(z, out);
}

// Round 2
// 727.192 us; speedup vs baseline: 1.0793x; 1.0793x over previous
//
#include <hip/hip_runtime.h>

// x: (1, 64, 32, 64, 64) f32   -> NN-upsample 2x2x2 -> (1,64,64,128,128)
// y = einsum('ncdhw,oc->nodhw', u, W) + b
// z: (1, 64, 68, 132, 132) f32 -> center crop (off 2,2,2) -> (1,64,64,128,128)
// out = concat([y, zc], axis=1): (1, 128, 64, 128, 128) f32

#define XC   64
#define XD   32
#define XH   64
#define XW   64
#define XPL  (XD * XH * XW)                  // 131072 floats per input channel

#define OD   64
#define OH   128
#define OW   128
#define OCH_STRIDE ((size_t)OD * OH * OW)    // 1,048,576 floats per out channel

#define ZD   68
#define ZH   132
#define ZW   132

// ---------------------------------------------------------------------------
// Kernel 1: upsample + 1x1x1 conv, o-split 2 via blockIdx.y.
// One thread per x position (d,h,w); wave = full w-row (w == lane).
// Per o: 64-FMA dot (2 partial chains), then 2 shfls rearrange the wave's
// accs into the replicated row pattern [a,a,b,b,...] so one wave store
// covers rows (2d,2h) and (2d,2h+1) = 1 KiB fully contiguous float4s.
// ---------------------------------------------------------------------------
__global__ __launch_bounds__(256) void upconv_kernel(
    const float* __restrict__ x, const float* __restrict__ W,
    const float* __restrict__ b, float* __restrict__ out) {
  const int pos  = blockIdx.x * 256 + threadIdx.x;   // 0 .. 131071
  const int lane = threadIdx.x & 63;                 // == w
  const int h = (pos >> 6) & 63;
  const int d = pos >> 12;

  float xv[XC];
#pragma unroll
  for (int c = 0; c < XC; ++c) xv[c] = x[(size_t)c * XPL + pos];

  const int j    = lane & 31;     // float4 index within output row
  const int rsel = lane >> 5;     // 0 -> row 2h, 1 -> row 2h+1
  const size_t base0 = ((size_t)(2 * d) * OH + (2 * h + rsel)) * OW + 4 * j;
  const size_t planeStride = (size_t)OH * OW;        // to plane 2d+1

  const int o_begin = blockIdx.y * 32;
#pragma unroll 4
  for (int oi = 0; oi < 32; ++oi) {
    const int o = o_begin + oi;
    float s0 = 0.f, s1 = 0.f;
#pragma unroll
    for (int c = 0; c < 32; ++c) {
      s0 += W[o * XC + c]      * xv[c];
      s1 += W[o * XC + 32 + c] * xv[32 + c];
    }
    const float acc = b[o] + s0 + s1;
    const float a  = __shfl(acc, 2 * j);
    const float bb = __shfl(acc, 2 * j + 1);
    const float4 v = make_float4(a, a, bb, bb);
    float* p = out + (size_t)o * OCH_STRIDE + base0;
    *(float4*)(p)               = v;   // plane 2d,   rows 2h / 2h+1 (1 KiB/wave)
    *(float4*)(p + planeStride) = v;   // plane 2d+1, rows 2h / 2h+1
  }
}

// ---------------------------------------------------------------------------
// Kernel 2: center-crop z -> out channels 64..127.
// 4 consecutive w floats per thread; src rows are 8B-aligned -> 2x float2
// loads; dst 16B-aligned -> float4 store.
// ---------------------------------------------------------------------------
__global__ __launch_bounds__(256) void cropcat_kernel(
    const float* __restrict__ z, float* __restrict__ out) {
  const unsigned u = blockIdx.x * 256u + threadIdx.x;  // 0 .. 2^24-1
  const int w4 = (u & 31) << 2;
  const int h  = (u >> 5) & 127;
  const int d  = (u >> 12) & 63;
  const int c  = u >> 18;

  const float* src = z + ((size_t)((c * ZD + d + 2) * ZH + (h + 2))) * ZW + (w4 + 2);
  const float2 a  = *(const float2*)(src);
  const float2 bb = *(const float2*)(src + 2);

  float* dst = out + (size_t)(64 + c) * OCH_STRIDE + ((size_t)d * OH + h) * OW + w4;
  *(float4*)dst = make_float4(a.x, a.y, bb.x, bb.y);
}

extern "C" void kernel_launch(void* const* d_in, const int* in_sizes, int n_in,
                              void* d_out, int out_size, void* d_ws, size_t ws_size,
                              hipStream_t stream) {
  const float* x = (const float*)d_in[0];
  const float* z = (const float*)d_in[1];
  const float* W = (const float*)d_in[2];
  const float* b = (const float*)d_in[3];
  float* out = (float*)d_out;

  dim3 grid1(512, 2);                       // 131072 positions, o-split 2
  upconv_kernel<<<grid1, 256, 0, stream>>>(x, W, b, out);

  cropcat_kernel<<<65536, 256, 0, stream>>>(z, out);
}